// Round 1
// baseline (5667.939 us; speedup 1.0000x reference)
//
#include <hip/hip_runtime.h>
#include <math.h>

#define NC 192        // channels
#define HH 256        // image H = W
#define WS 8          // window size
#define SHIFT 4
#define NHEADS 6
#define CPH 32        // channels per head
#define NPIX 64       // pixels per window
#define XS_STRIDE 194 // ushorts per pixel row (192 + 2 pad) -> conflict-free
#define RAW_STRIDE 65 // floats per channel row (64 + 1 pad)
#define AS_STRIDE 33  // attn matrix row stride

__device__ __forceinline__ float bf2f(unsigned short h) {
    union { unsigned int u; float f; } v; v.u = ((unsigned int)h) << 16; return v.f;
}
__device__ __forceinline__ unsigned short f2bf(float f) {
    union { float f; unsigned int u; } v; v.f = f;
    unsigned int u = v.u + 0x7FFFu + ((v.u >> 16) & 1u);
    return (unsigned short)(u >> 16);
}

// LDS layout (phase 1): xs bf16 [64][194]  = 24832 B
//                       raw f32 [96][65]   = 24960 B
//                       attn f32 [32][33]  =  4224 B   total 54016 B
// LDS layout (phase 2): oall f32 [192][64] = 49152 B (overlays everything)
#define SMEM_BYTES 54016
#define RAW_OFF    24832
#define AS_OFF     (24832 + 24960)

__global__ __launch_bounds__(256, 2) void attn_win_kernel(
    const float* __restrict__ x, const float* __restrict__ qkv_w,
    const float* __restrict__ dw_w, const float* __restrict__ proj_w,
    const float* __restrict__ temperature, float* __restrict__ out)
{
    __shared__ __align__(16) unsigned char smem[SMEM_BYTES];
    unsigned short* xs = (unsigned short*)smem;          // [64][XS_STRIDE]
    float* raw = (float*)(smem + RAW_OFF);               // [96][RAW_STRIDE]
    float* as_ = (float*)(smem + AS_OFF);                // [32][AS_STRIDE]
    float* oall = (float*)smem;                          // phase 2: [192][64]

    const int t  = threadIdx.x;
    const int blk = blockIdx.x;
    const int b  = blk >> 10;          // image
    const int wi = (blk >> 5) & 31;    // window row
    const int wj = blk & 31;           // window col

    // ---- load x window (rolled by -SHIFT) into xs as bf16, pixel-major ----
    for (int idx = t; idx < NC * NPIX; idx += 256) {
        int c = idx >> 6, p = idx & 63;
        int r = p >> 3, s = p & 7;
        int hh = (wi * WS + r + SHIFT) & 255;
        int ww = (wj * WS + s + SHIFT) & 255;
        float v = x[((size_t)(b * NC + c) * HH + hh) * HH + ww];
        xs[p * XS_STRIDE + c] = f2bf(v);
    }
    __syncthreads();

    const int p  = t & 63;   // pixel within window
    const int wv = t >> 6;   // wave id 0..3
    const int r  = p >> 3, s = p & 7;
    const ushort2* xrow = (const ushort2*)(xs + p * XS_STRIDE);

    float outreg[48];
    #pragma unroll
    for (int i = 0; i < 48; ++i) outreg[i] = 0.f;

    for (int h = 0; h < NHEADS; ++h) {
        // ---- 1. qkv 1x1 matmul: wave wv computes raw rows wv*24..+23 ----
        for (int ob = 0; ob < 24; ob += 4) {
            int rr0 = wv * 24 + ob;
            int g0  = (rr0 >> 5) * NC + h * CPH + (rr0 & 31);
            const float4* w0 = (const float4*)(qkv_w + (size_t)(g0 + 0) * NC);
            const float4* w1 = (const float4*)(qkv_w + (size_t)(g0 + 1) * NC);
            const float4* w2 = (const float4*)(qkv_w + (size_t)(g0 + 2) * NC);
            const float4* w3 = (const float4*)(qkv_w + (size_t)(g0 + 3) * NC);
            float a0 = 0.f, a1 = 0.f, a2 = 0.f, a3 = 0.f;
            for (int c4 = 0; c4 < NC / 4; ++c4) {
                ushort2 xa = xrow[c4 * 2], xb = xrow[c4 * 2 + 1];
                float x0 = bf2f(xa.x), x1 = bf2f(xa.y);
                float x2 = bf2f(xb.x), x3 = bf2f(xb.y);
                float4 ww;
                ww = w0[c4]; a0 += ww.x*x0 + ww.y*x1 + ww.z*x2 + ww.w*x3;
                ww = w1[c4]; a1 += ww.x*x0 + ww.y*x1 + ww.z*x2 + ww.w*x3;
                ww = w2[c4]; a2 += ww.x*x0 + ww.y*x1 + ww.z*x2 + ww.w*x3;
                ww = w3[c4]; a3 += ww.x*x0 + ww.y*x1 + ww.z*x2 + ww.w*x3;
            }
            raw[(rr0 + 0) * RAW_STRIDE + p] = a0;
            raw[(rr0 + 1) * RAW_STRIDE + p] = a1;
            raw[(rr0 + 2) * RAW_STRIDE + p] = a2;
            raw[(rr0 + 3) * RAW_STRIDE + p] = a3;
        }
        __syncthreads();   // A: raw (pre-dw) visible

        // ---- 2. depthwise 3x3 (zero pad within window) + l2norm for q,k ----
        float dwv[24];
        #pragma unroll
        for (int i = 0; i < 24; ++i) {
            int rr = wv * 24 + i;
            int g  = (rr >> 5) * NC + h * CPH + (rr & 31);
            const float* wp = dw_w + (size_t)g * 9;
            float a = 0.f;
            #pragma unroll
            for (int dy = -1; dy <= 1; ++dy) {
                int r2 = r + dy;
                if ((unsigned)r2 < 8u) {
                    #pragma unroll
                    for (int dx = -1; dx <= 1; ++dx) {
                        int s2 = s + dx;
                        if ((unsigned)s2 < 8u)
                            a += wp[(dy + 1) * 3 + (dx + 1)] * raw[rr * RAW_STRIDE + r2 * 8 + s2];
                    }
                }
            }
            dwv[i] = a;
        }
        // l2 norm across the 64 pixels (wave butterfly) for q,k rows (rr<64)
        #pragma unroll
        for (int i = 0; i < 24; ++i) {
            int rr = wv * 24 + i;
            if (rr < 64) {
                float ss = dwv[i] * dwv[i];
                #pragma unroll
                for (int m = 1; m < 64; m <<= 1) ss += __shfl_xor(ss, m, 64);
                float nrm = sqrtf(ss);
                dwv[i] *= 1.0f / fmaxf(nrm, 1e-12f);
            }
        }
        __syncthreads();   // B: all raw reads done before overwrite
        #pragma unroll
        for (int i = 0; i < 24; ++i)
            raw[(wv * 24 + i) * RAW_STRIDE + p] = dwv[i];
        __syncthreads();   // C: dw'd + normalized q,k,v visible

        // ---- 3. attn logits: 2x2 per thread over 32x32 ----
        {
            int i0 = (t >> 4) * 2;
            int j0 = (t & 15) * 2;
            const float* qr0 = raw + (i0 + 0) * RAW_STRIDE;
            const float* qr1 = raw + (i0 + 1) * RAW_STRIDE;
            const float* kr0 = raw + (32 + j0) * RAW_STRIDE;
            const float* kr1 = raw + (33 + j0) * RAW_STRIDE;
            float s00 = 0.f, s01 = 0.f, s10 = 0.f, s11 = 0.f;
            for (int pp = 0; pp < 64; ++pp) {
                float q0 = qr0[pp], q1 = qr1[pp];
                float k0 = kr0[pp], k1 = kr1[pp];
                s00 += q0 * k0; s01 += q0 * k1;
                s10 += q1 * k0; s11 += q1 * k1;
            }
            float tmp = temperature[h];
            as_[(i0 + 0) * AS_STRIDE + j0 + 0] = s00 * tmp;
            as_[(i0 + 0) * AS_STRIDE + j0 + 1] = s01 * tmp;
            as_[(i0 + 1) * AS_STRIDE + j0 + 0] = s10 * tmp;
            as_[(i0 + 1) * AS_STRIDE + j0 + 1] = s11 * tmp;
        }
        __syncthreads();   // D

        // ---- 4. softmax over last dim (rows of 32) ----
        if (t < 32) {
            float* rowp = as_ + t * AS_STRIDE;
            float mx = rowp[0];
            for (int j = 1; j < 32; ++j) mx = fmaxf(mx, rowp[j]);
            float sum = 0.f;
            for (int j = 0; j < 32; ++j) { float e = __expf(rowp[j] - mx); rowp[j] = e; sum += e; }
            float inv = 1.0f / sum;
            for (int j = 0; j < 32; ++j) rowp[j] *= inv;
        }
        __syncthreads();   // E

        // ---- 5. out = attn @ v, accumulate in registers ----
        {
            float acc[8];
            #pragma unroll
            for (int ii = 0; ii < 8; ++ii) acc[ii] = 0.f;
            for (int j = 0; j < 32; ++j) {
                float vv = raw[(64 + j) * RAW_STRIDE + p];
                #pragma unroll
                for (int ii = 0; ii < 8; ++ii)
                    acc[ii] += as_[(wv * 8 + ii) * AS_STRIDE + j] * vv;
            }
            #pragma unroll
            for (int ii = 0; ii < 8; ++ii) outreg[h * 8 + ii] = acc[ii];
        }
        __syncthreads();   // F: raw/as_ free for next head
    }

    // ---- phase 2: stage attention output, then proj 1x1 and store ----
    #pragma unroll
    for (int h2 = 0; h2 < NHEADS; ++h2)
        #pragma unroll
        for (int ii = 0; ii < 8; ++ii)
            oall[(h2 * CPH + wv * 8 + ii) * 64 + p] = outreg[h2 * 8 + ii];
    __syncthreads();

    const int hh2 = (wi * WS + r + SHIFT) & 255;
    const int ww2 = (wj * WS + s + SHIFT) & 255;
    for (int ob = 0; ob < 48; ob += 4) {
        int o0 = wv * 48 + ob;
        const float4* w0 = (const float4*)(proj_w + (size_t)(o0 + 0) * NC);
        const float4* w1 = (const float4*)(proj_w + (size_t)(o0 + 1) * NC);
        const float4* w2 = (const float4*)(proj_w + (size_t)(o0 + 2) * NC);
        const float4* w3 = (const float4*)(proj_w + (size_t)(o0 + 3) * NC);
        float a0 = 0.f, a1 = 0.f, a2 = 0.f, a3 = 0.f;
        for (int c4 = 0; c4 < NC / 4; ++c4) {
            float x0 = oall[(c4 * 4 + 0) * 64 + p];
            float x1 = oall[(c4 * 4 + 1) * 64 + p];
            float x2 = oall[(c4 * 4 + 2) * 64 + p];
            float x3 = oall[(c4 * 4 + 3) * 64 + p];
            float4 ww;
            ww = w0[c4]; a0 += ww.x*x0 + ww.y*x1 + ww.z*x2 + ww.w*x3;
            ww = w1[c4]; a1 += ww.x*x0 + ww.y*x1 + ww.z*x2 + ww.w*x3;
            ww = w2[c4]; a2 += ww.x*x0 + ww.y*x1 + ww.z*x2 + ww.w*x3;
            ww = w3[c4]; a3 += ww.x*x0 + ww.y*x1 + ww.z*x2 + ww.w*x3;
        }
        out[((size_t)(b * NC + o0 + 0) * HH + hh2) * HH + ww2] = a0;
        out[((size_t)(b * NC + o0 + 1) * HH + hh2) * HH + ww2] = a1;
        out[((size_t)(b * NC + o0 + 2) * HH + hh2) * HH + ww2] = a2;
        out[((size_t)(b * NC + o0 + 3) * HH + hh2) * HH + ww2] = a3;
    }
}

extern "C" void kernel_launch(void* const* d_in, const int* in_sizes, int n_in,
                              void* d_out, int out_size, void* d_ws, size_t ws_size,
                              hipStream_t stream) {
    const float* x           = (const float*)d_in[0];
    const float* qkv_w       = (const float*)d_in[1];
    const float* dw_w        = (const float*)d_in[2];
    const float* proj_w      = (const float*)d_in[3];
    const float* temperature = (const float*)d_in[4];
    float* out = (float*)d_out;

    dim3 grid(4 * 32 * 32);
    dim3 block(256);
    hipLaunchKernelGGL(attn_win_kernel, grid, block, 0, stream,
                       x, qkv_w, dw_w, proj_w, temperature, out);
}

// Round 2
// 878.601 us; speedup vs baseline: 6.4511x; 6.4511x over previous
//
#include <hip/hip_runtime.h>
#include <math.h>

typedef short bf16x8 __attribute__((ext_vector_type(8)));
typedef float floatx4 __attribute__((ext_vector_type(4)));

#define NC 192
#define HH 256
#define WSZ 8
#define NSHIFT 4
#define NHEADS 6

// LDS map (bytes):
//  region A [0, 26112): phase0 xstage (24576) / per-head qkvh f32[96][68] (26112)
//                       after pack: attnb f32[32][36] @0 (4608), obuf f32[64][36] @4608 (9216)
//  frags [26112, 40448): 14 frags x 1024 B  (q:0-3, k:4-7, v:8-11, a:12-13)
//  scale [40448, 40704): f32[64]
#define QKVH_STRIDE 68
#define ATTN_STRIDE 36
#define OBUF_STRIDE 36
#define FRAG_OFF 26112
#define SCALE_OFF 40448
#define LDS_TOTAL 40704

#define QKV_FRAG_ELEMS (576 * 192)   // ws: qkv frags then proj frags (bf16)

__device__ __forceinline__ unsigned short f2bf(float f) {
    union { float f; unsigned int u; } v; v.f = f;
    unsigned int u = v.u + 0x7FFFu + ((v.u >> 16) & 1u);
    return (unsigned short)(u >> 16);
}

// ---- preprocess: swizzle qkv_w / proj_w (f32 row-major) into bf16 MFMA A-frags ----
// A-frag for tile (mt, kt): lane l, j in [0,8): A[mt*16 + (l&15)][kt*32 + (l>>4)*8 + j]
// stored at ws[((mt*6 + kt)*64 + l)*8 + j]
__global__ void preproc_kernel(const float* __restrict__ qkv_w,
                               const float* __restrict__ proj_w,
                               unsigned short* __restrict__ ws) {
    int e = blockIdx.x * 256 + threadIdx.x;
    if (e < QKV_FRAG_ELEMS) {
        int blk = e >> 9, l = (e >> 3) & 63, j = e & 7;
        int mt = blk / 6, kt = blk % 6;
        ws[e] = f2bf(qkv_w[(mt * 16 + (l & 15)) * NC + kt * 32 + (l >> 4) * 8 + j]);
    } else if (e < QKV_FRAG_ELEMS + NC * NC) {
        int e2 = e - QKV_FRAG_ELEMS;
        int blk = e2 >> 9, l = (e2 >> 3) & 63, j = e2 & 7;
        int mt = blk / 6, kt = blk % 6;
        ws[e] = f2bf(proj_w[(mt * 16 + (l & 15)) * NC + kt * 32 + (l >> 4) * 8 + j]);
    }
}

__global__ __launch_bounds__(256, 3) void attn_main(
    const float* __restrict__ x, const unsigned short* __restrict__ wsA,
    const float* __restrict__ dw_w, const float* __restrict__ temperature,
    float* __restrict__ out)
{
    __shared__ __align__(16) unsigned char smem[LDS_TOTAL];
    float* qkvh = (float*)smem;
    unsigned short* xstage = (unsigned short*)smem;
    float* attnb = (float*)smem;                       // [32][36]
    float* obuf  = (float*)(smem + 4608);              // [64][36]
    unsigned short* frags = (unsigned short*)(smem + FRAG_OFF);
    float* scale = (float*)(smem + SCALE_OFF);

    const int t = threadIdx.x;
    const int lane = t & 63;
    const int wv = t >> 6;          // wave id == n-tile (16 px) owned by this wave
    const int quad = lane >> 4;
    const int l15 = lane & 15;
    const int blk = blockIdx.x;
    const int b = blk >> 10, wi = (blk >> 5) & 31, wj = blk & 31;

    // ---- stage x window (rolled -4) into B-frag layout, bf16 ----
    for (int idx = t; idx < NC * 64; idx += 256) {
        int c = idx >> 6, p = idx & 63;
        int r = p >> 3, s = p & 7;
        int hh = (wi * WSZ + r + NSHIFT) & 255;
        int ww = (wj * WSZ + s + NSHIFT) & 255;
        float v = x[((size_t)(b * NC + c) * HH + hh) * HH + ww];
        int kt = c >> 5, ko = c & 31;
        int fr = kt * 4 + (p >> 4);
        int lx = ((ko >> 3) << 4) | (p & 15);
        xstage[(fr * 64 + lx) * 8 + (ko & 7)] = f2bf(v);
    }
    __syncthreads();

    bf16x8 Bx[6];
    #pragma unroll
    for (int kt = 0; kt < 6; ++kt)
        Bx[kt] = *((const bf16x8*)(xstage + ((kt * 4 + wv) * 64 + lane) * 8));
    __syncthreads();   // xstage region free -> qkvh

    bf16x8 pB0, pB1, pB2, pB3, pB4, pB5;   // proj B-frags accumulated per head

    #pragma unroll 1
    for (int h = 0; h < NHEADS; ++h) {
        // ---- 1. qkv GEMM for head h: 6 m-tiles of 16 rows ----
        #pragma unroll
        for (int mtl = 0; mtl < 6; ++mtl) {
            int part = mtl >> 1, sub = mtl & 1;
            int mt_g = part * 12 + h * 2 + sub;
            const bf16x8* aptr = (const bf16x8*)wsA + (size_t)(mt_g * 6) * 64 + lane;
            floatx4 acc = {0.f, 0.f, 0.f, 0.f};
            #pragma unroll
            for (int kt = 0; kt < 6; ++kt) {
                bf16x8 a = aptr[kt * 64];
                acc = __builtin_amdgcn_mfma_f32_16x16x32_bf16(a, Bx[kt], acc, 0, 0, 0);
            }
            int rowbase = part * 32 + sub * 16 + quad * 4;
            int col = wv * 16 + l15;
            #pragma unroll
            for (int rg = 0; rg < 4; ++rg)
                qkvh[(rowbase + rg) * QKVH_STRIDE + col] = acc[rg];
        }
        __syncthreads();   // S1: qkvh visible

        // ---- 2. depthwise 3x3, zero-pad inside window ----
        float dwout[4][8];
        if (t < 192) {
            int ch = t >> 1, half = t & 1;
            int part = ch >> 5;
            int g = part * NC + h * 32 + (ch & 31);
            const float* wp = dw_w + (size_t)g * 9;
            float w[9];
            #pragma unroll
            for (int i = 0; i < 9; ++i) w[i] = wp[i];
            const float* base = qkvh + ch * QKVH_STRIDE;
            int r0 = half * 4;
            float ra[8], rb[8], rc[8];
            auto loadrow = [&](float* dst, int r2) {
                if ((unsigned)r2 < 8u) {
                    float4 lo = *((const float4*)(base + r2 * 8));
                    float4 hi = *((const float4*)(base + r2 * 8 + 4));
                    dst[0]=lo.x; dst[1]=lo.y; dst[2]=lo.z; dst[3]=lo.w;
                    dst[4]=hi.x; dst[5]=hi.y; dst[6]=hi.z; dst[7]=hi.w;
                } else {
                    #pragma unroll
                    for (int i = 0; i < 8; ++i) dst[i] = 0.f;
                }
            };
            auto conv3 = [&](float* o, const float* rm, const float* rz, const float* rp) {
                #pragma unroll
                for (int s = 0; s < 8; ++s) {
                    float acc = w[1]*rm[s] + w[4]*rz[s] + w[7]*rp[s];
                    if (s > 0) acc += w[0]*rm[s-1] + w[3]*rz[s-1] + w[6]*rp[s-1];
                    if (s < 7) acc += w[2]*rm[s+1] + w[5]*rz[s+1] + w[8]*rp[s+1];
                    o[s] = acc;
                }
            };
            loadrow(ra, r0 - 1); loadrow(rb, r0); loadrow(rc, r0 + 1);
            conv3(dwout[0], ra, rb, rc);
            loadrow(ra, r0 + 2); conv3(dwout[1], rb, rc, ra);
            loadrow(rb, r0 + 3); conv3(dwout[2], rc, ra, rb);
            loadrow(rc, r0 + 4); conv3(dwout[3], ra, rb, rc);
        }
        __syncthreads();   // S2: all dw reads complete
        if (t < 192) {
            int ch = t >> 1, half = t & 1;
            float* dst = qkvh + ch * QKVH_STRIDE + half * 32;
            #pragma unroll
            for (int ro = 0; ro < 4; ++ro) {
                *((float4*)(dst + ro * 8))     = make_float4(dwout[ro][0], dwout[ro][1], dwout[ro][2], dwout[ro][3]);
                *((float4*)(dst + ro * 8 + 4)) = make_float4(dwout[ro][4], dwout[ro][5], dwout[ro][6], dwout[ro][7]);
            }
        }
        __syncthreads();   // S3: dw'd qkvh visible

        // ---- 3. l2-norm scales for q,k (rows 0..63): ch = t>>2, slice = t&3 ----
        {
            int ch = t >> 2, sl = t & 3;
            const float4* src = (const float4*)(qkvh + ch * QKVH_STRIDE + sl * 16);
            float ss = 0.f;
            #pragma unroll
            for (int i = 0; i < 4; ++i) {
                float4 v = src[i];
                ss += v.x*v.x + v.y*v.y + v.z*v.z + v.w*v.w;
            }
            ss += __shfl_xor(ss, 1, 64);
            ss += __shfl_xor(ss, 2, 64);
            if (sl == 0) scale[ch] = 1.0f / fmaxf(sqrtf(ss), 1e-12f);
        }
        __syncthreads();   // S4: scales visible

        // ---- 4. pack q,k,v into bf16 frags (each wave builds 3) ----
        {
            int mt = wv >> 1, kt = wv & 1;
            // q frag id = wv
            {
                int ch = mt * 16 + l15;
                const float* src = qkvh + ch * QKVH_STRIDE + kt * 32 + quad * 8;
                float4 lo = *((const float4*)src), hi = *((const float4*)(src + 4));
                float sc = scale[ch];
                float v[8] = {lo.x*sc, lo.y*sc, lo.z*sc, lo.w*sc, hi.x*sc, hi.y*sc, hi.z*sc, hi.w*sc};
                bf16x8 o;
                #pragma unroll
                for (int i = 0; i < 8; ++i) o[i] = (short)f2bf(v[i]);
                *((bf16x8*)(frags + wv * 512 + lane * 8)) = o;
            }
            // k frag id = 4 + wv
            {
                int ch = 32 + mt * 16 + l15;
                const float* src = qkvh + ch * QKVH_STRIDE + kt * 32 + quad * 8;
                float4 lo = *((const float4*)src), hi = *((const float4*)(src + 4));
                float sc = scale[ch];
                float v[8] = {lo.x*sc, lo.y*sc, lo.z*sc, lo.w*sc, hi.x*sc, hi.y*sc, hi.z*sc, hi.w*sc};
                bf16x8 o;
                #pragma unroll
                for (int i = 0; i < 8; ++i) o[i] = (short)f2bf(v[i]);
                *((bf16x8*)(frags + (4 + wv) * 512 + lane * 8)) = o;
            }
            // v frag id = 8 + wv  (column gather, no norm)
            {
                int px = wv * 16 + l15;
                int chb = 64 + quad * 8;
                bf16x8 o;
                #pragma unroll
                for (int j = 0; j < 8; ++j) o[j] = (short)f2bf(qkvh[(chb + j) * QKVH_STRIDE + px]);
                *((bf16x8*)(frags + (8 + wv) * 512 + lane * 8)) = o;
            }
        }
        __syncthreads();   // S5: frags ready; qkvh rows <51 now dead

        // ---- 5. QK^T (one 16x16 tile per wave) ----
        {
            int mt = wv >> 1, ntk = wv & 1;
            floatx4 acc = {0.f, 0.f, 0.f, 0.f};
            #pragma unroll
            for (int kt = 0; kt < 2; ++kt) {
                bf16x8 aq = *((const bf16x8*)(frags + (mt * 2 + kt) * 512 + lane * 8));
                bf16x8 bk = *((const bf16x8*)(frags + (4 + ntk * 2 + kt) * 512 + lane * 8));
                acc = __builtin_amdgcn_mfma_f32_16x16x32_bf16(aq, bk, acc, 0, 0, 0);
            }
            float tmp = temperature[h];
            #pragma unroll
            for (int rg = 0; rg < 4; ++rg)
                attnb[(mt * 16 + quad * 4 + rg) * ATTN_STRIDE + ntk * 16 + l15] = acc[rg] * tmp;
        }
        __syncthreads();   // S6

        // ---- 6. softmax + A-frag emit (threads 0..127: row = t>>2, slice = t&3) ----
        if (t < 128) {
            int row = t >> 2, sl = t & 3;
            const float* src = attnb + row * ATTN_STRIDE + sl * 8;
            float4 lo = *((const float4*)src), hi = *((const float4*)(src + 4));
            float v[8] = {lo.x, lo.y, lo.z, lo.w, hi.x, hi.y, hi.z, hi.w};
            float mx = v[0];
            #pragma unroll
            for (int i = 1; i < 8; ++i) mx = fmaxf(mx, v[i]);
            mx = fmaxf(mx, __shfl_xor(mx, 1, 64));
            mx = fmaxf(mx, __shfl_xor(mx, 2, 64));
            float sum = 0.f;
            #pragma unroll
            for (int i = 0; i < 8; ++i) { v[i] = __expf(v[i] - mx); sum += v[i]; }
            sum += __shfl_xor(sum, 1, 64);
            sum += __shfl_xor(sum, 2, 64);
            float inv = 1.0f / sum;
            bf16x8 o;
            #pragma unroll
            for (int i = 0; i < 8; ++i) o[i] = (short)f2bf(v[i] * inv);
            *((bf16x8*)(frags + (12 + (row >> 4)) * 512 + (sl * 16 + (row & 15)) * 8)) = o;
        }
        __syncthreads();   // S7

        // ---- 7. attn @ V -> obuf[px][ch] ----
        {
            bf16x8 bv = *((const bf16x8*)(frags + (8 + wv) * 512 + lane * 8));
            #pragma unroll
            for (int mt = 0; mt < 2; ++mt) {
                bf16x8 aa = *((const bf16x8*)(frags + (12 + mt) * 512 + lane * 8));
                floatx4 acc = {0.f, 0.f, 0.f, 0.f};
                acc = __builtin_amdgcn_mfma_f32_16x16x32_bf16(aa, bv, acc, 0, 0, 0);
                #pragma unroll
                for (int rg = 0; rg < 4; ++rg)
                    obuf[(wv * 16 + l15) * OBUF_STRIDE + mt * 16 + quad * 4 + rg] = acc[rg];
            }
        }
        __syncthreads();   // S8

        // ---- 8. pack O into this wave's proj B-frag (kt = h) ----
        {
            const float* src = obuf + (wv * 16 + l15) * OBUF_STRIDE + quad * 8;
            float4 lo = *((const float4*)src), hi = *((const float4*)(src + 4));
            float v[8] = {lo.x, lo.y, lo.z, lo.w, hi.x, hi.y, hi.z, hi.w};
            bf16x8 o;
            #pragma unroll
            for (int i = 0; i < 8; ++i) o[i] = (short)f2bf(v[i]);
            switch (h) {
                case 0: pB0 = o; break;
                case 1: pB1 = o; break;
                case 2: pB2 = o; break;
                case 3: pB3 = o; break;
                case 4: pB4 = o; break;
                default: pB5 = o; break;
            }
        }
        __syncthreads();   // S9: obuf reads done before next head's qkvh writes
    }

    // ---- proj GEMM: 12 m-tiles, nt = wv; direct global store (roll +4) ----
    const bf16x8* apro = (const bf16x8*)(wsA + QKV_FRAG_ELEMS);
    int px = wv * 16 + l15;
    int r = px >> 3, s = px & 7;
    int hh = (wi * WSZ + r + NSHIFT) & 255;
    int ww = (wj * WSZ + s + NSHIFT) & 255;
    #pragma unroll
    for (int mt = 0; mt < 12; ++mt) {
        const bf16x8* ap = apro + (size_t)(mt * 6) * 64 + lane;
        floatx4 acc = {0.f, 0.f, 0.f, 0.f};
        acc = __builtin_amdgcn_mfma_f32_16x16x32_bf16(ap[0 * 64], pB0, acc, 0, 0, 0);
        acc = __builtin_amdgcn_mfma_f32_16x16x32_bf16(ap[1 * 64], pB1, acc, 0, 0, 0);
        acc = __builtin_amdgcn_mfma_f32_16x16x32_bf16(ap[2 * 64], pB2, acc, 0, 0, 0);
        acc = __builtin_amdgcn_mfma_f32_16x16x32_bf16(ap[3 * 64], pB3, acc, 0, 0, 0);
        acc = __builtin_amdgcn_mfma_f32_16x16x32_bf16(ap[4 * 64], pB4, acc, 0, 0, 0);
        acc = __builtin_amdgcn_mfma_f32_16x16x32_bf16(ap[5 * 64], pB5, acc, 0, 0, 0);
        int chb = mt * 16 + quad * 4;
        #pragma unroll
        for (int rg = 0; rg < 4; ++rg)
            out[((size_t)(b * NC + chb + rg) * HH + hh) * HH + ww] = acc[rg];
    }
}

extern "C" void kernel_launch(void* const* d_in, const int* in_sizes, int n_in,
                              void* d_out, int out_size, void* d_ws, size_t ws_size,
                              hipStream_t stream) {
    const float* x           = (const float*)d_in[0];
    const float* qkv_w       = (const float*)d_in[1];
    const float* dw_w        = (const float*)d_in[2];
    const float* proj_w      = (const float*)d_in[3];
    const float* temperature = (const float*)d_in[4];
    float* out = (float*)d_out;
    unsigned short* wsA = (unsigned short*)d_ws;

    // swizzle weights to bf16 MFMA A-fragments (runs every call; ~150K elems)
    int total = QKV_FRAG_ELEMS + NC * NC;
    hipLaunchKernelGGL(preproc_kernel, dim3((total + 255) / 256), dim3(256), 0, stream,
                       qkv_w, proj_w, wsA);
    hipLaunchKernelGGL(attn_main, dim3(4 * 32 * 32), dim3(256), 0, stream,
                       x, wsA, dw_w, temperature, out);
}